// Round 4
// baseline (365.847 us; speedup 1.0000x reference)
//
#include <hip/hip_runtime.h>

#define N_NODES 50000
#define NHALF 25000
#define N_EDGES 1600000
#define HD 64    // H*D
#define NH 8     // heads
#define NBKT 196 // dst buckets (dst >> 8)
#define EPB 8192 // edges per block in binning passes
#define GB1 196  // ceil(N_EDGES / EPB)
#define SCAN_M (NBKT * GB1)   // 38416
#define NB2 151               // ceil(SCAN_M / 256)
#define DCAP 8960             // pass-D LDS edge capacity (mean 8192, +8.5 sigma)
#define SEGB 2048             // 256 dst-low bins x 8 src segments
#define GBN 196               // ceil(N_NODES / 256) node blocks for gemm

__device__ inline int wave_incl_scan(int v, int lane) {
#pragma unroll
    for (int o = 1; o < 64; o <<= 1) {
        int t = __shfl_up(v, o);
        if (lane >= o) v += t;
    }
    return v;
}

// ------------------------------------------------- GEMM + attention logits
// PROVEN config: thread = node, 16 output features (= 2 complete heads),
// 4 y-blocks. x re-reads are L3-absorbed; narrow tile keeps VGPR/SGPR
// pressure low -> deep load pipelining. 32/64-wide measured SLOWER.
template <int F>
__device__ __forceinline__ void gemm_body16(
    int bx, int by, int t,
    const float* __restrict__ x, const float* __restrict__ W,
    const float* __restrict__ att,
    _Float16* __restrict__ h, float* __restrict__ es, float* __restrict__ ed) {
    int n = bx * 256 + t;
    int f0 = by * 16;
    int nc = (n < N_NODES) ? n : (N_NODES - 1);
    const float4* xrow = (const float4*)x + (size_t)nc * (F / 4);
    float acc[16];
#pragma unroll
    for (int i = 0; i < 16; i++) acc[i] = 0.f;
#pragma unroll 4
    for (int kk = 0; kk < F / 4; kk++) {
        float4 xv = xrow[kk];
        const float* Wk = W + (kk * 4) * 64 + f0;  // wave-uniform base
#pragma unroll
        for (int i = 0; i < 16; i++)
            acc[i] += xv.x * Wk[i] + xv.y * Wk[64 + i] +
                      xv.z * Wk[128 + i] + xv.w * Wk[192 + i];
    }
    if (n >= N_NODES) return;

    float s0 = 0.f, s1 = 0.f, d0 = 0.f, d1 = 0.f;
#pragma unroll
    for (int i = 0; i < 8; i++) {
        s0 += acc[i] * att[f0 + i];
        d0 += acc[i] * att[64 + f0 + i];
    }
#pragma unroll
    for (int i = 8; i < 16; i++) {
        s1 += acc[i] * att[f0 + i];
        d1 += acc[i] * att[64 + f0 + i];
    }
    int hh = f0 >> 3;
    es[n * NH + hh] = s0; es[n * NH + hh + 1] = s1;
    ed[n * NH + hh] = d0; ed[n * NH + hh + 1] = d1;

    union { _Float16 hf[16]; uint4 u[2]; } cv;
#pragma unroll
    for (int i = 0; i < 16; i++) cv.hf[i] = (_Float16)acc[i];
    uint4* hp = (uint4*)(h + (size_t)n * HD + f0);
    hp[0] = cv.u[0];
    hp[1] = cv.u[1];
}

template <int F>
__global__ __launch_bounds__(256) void gemm_att_kernel(
    const float* __restrict__ x, const float* __restrict__ W,
    const float* __restrict__ att,
    _Float16* __restrict__ h, float* __restrict__ es, float* __restrict__ ed) {
    gemm_body16<F>(blockIdx.x, blockIdx.y, threadIdx.x, x, W, att, h, es, ed);
}

// ---------------------------------------------------- CSR build (no global atomics)
// Fused: grid (GBN, 5). y<4 -> gemm layer0 y-block (hides histA); y==4 ->
// dst histogram block (GB1 == GBN == 196).
__global__ __launch_bounds__(256) void histA_gemm_kernel(
    const int* __restrict__ dst, int* __restrict__ offs,
    const float* __restrict__ x, const float* __restrict__ W,
    const float* __restrict__ att,
    _Float16* __restrict__ h, float* __restrict__ es, float* __restrict__ ed) {
    if (blockIdx.y < 4) {
        gemm_body16<128>(blockIdx.x, blockIdx.y, threadIdx.x, x, W, att, h, es, ed);
        return;
    }
    int bb = blockIdx.x;
    __shared__ int hist[NBKT];
    int t = threadIdx.x;
    if (t < NBKT) hist[t] = 0;
    __syncthreads();
    int base = bb * EPB;
#pragma unroll
    for (int k = 0; k < EPB / 256; k++) {
        int e = base + k * 256 + t;
        if (e < N_EDGES) atomicAdd(&hist[dst[e] >> 8], 1);
    }
    __syncthreads();
    if (t < NBKT) offs[t * GB1 + bb] = hist[t];
}

__global__ __launch_bounds__(256) void scanB1_kernel(int* __restrict__ offs,
                                                     int* __restrict__ part2) {
    __shared__ int wsum[4];
    int t = threadIdx.x, lane = t & 63, wv = t >> 6;
    int i = blockIdx.x * 256 + t;
    int v = (i < SCAN_M) ? offs[i] : 0;
    int inc = wave_incl_scan(v, lane);
    if (lane == 63) wsum[wv] = inc;
    __syncthreads();
    if (t == 0) {
        int a = 0;
        for (int k = 0; k < 4; k++) { int x = wsum[k]; wsum[k] = a; a += x; }
    }
    __syncthreads();
    int excl = wsum[wv] + inc - v;
    if (i < SCAN_M) offs[i] = excl;
    if (t == 255) part2[blockIdx.x] = wsum[wv] + inc;
}

// scanB2 folded into consumers: each block exclusive-scans part2 (151 ints) in LDS.
__global__ __launch_bounds__(256) void scatC_kernel(const int* __restrict__ src,
                                                    const int* __restrict__ dst,
                                                    const int* __restrict__ offs,
                                                    const int* __restrict__ part2,
                                                    unsigned* __restrict__ ebuf) {
    __shared__ int cur[NBKT];
    __shared__ int base_s[NBKT];
    __shared__ int p2s[256];
    __shared__ int p2w[4];
    int t = threadIdx.x, lane = t & 63, wv = t >> 6;
    int v = (t < NB2) ? part2[t] : 0;
    int inc = wave_incl_scan(v, lane);
    if (lane == 63) p2w[wv] = inc;
    __syncthreads();
    if (t == 0) {
        int a = 0;
        for (int k = 0; k < 4; k++) { int x = p2w[k]; p2w[k] = a; a += x; }
    }
    __syncthreads();
    p2s[t] = p2w[wv] + inc - v;
    if (t < NBKT) cur[t] = 0;
    __syncthreads();
    if (t < NBKT) {
        int f = t * GB1 + blockIdx.x;
        base_s[t] = offs[f] + p2s[f >> 8];
    }
    __syncthreads();
    int base = blockIdx.x * EPB;
#pragma unroll
    for (int k = 0; k < EPB / 256; k++) {
        int e = base + k * 256 + t;
        if (e < N_EDGES) {
            int d = dst[e];
            int b = d >> 8;
            int r = atomicAdd(&cur[b], 1);
            ebuf[base_s[b] + r] = (unsigned)src[e] | ((unsigned)(d & 255) << 16);
        }
    }
}

__global__ __launch_bounds__(512) void csrD_kernel(const int* __restrict__ offs,
                                                   const int* __restrict__ part2,
                                                   const unsigned* __restrict__ ebuf,
                                                   int* __restrict__ rowptr,
                                                   unsigned short* __restrict__ csr) {
    __shared__ unsigned eb[DCAP];
    __shared__ int hist[SEGB];
    __shared__ int wsum[8];
    __shared__ int p2s[512];
    int b = blockIdx.x, t = threadIdx.x;
    int lane = t & 63, wv = t >> 6;
    {   // in-block exclusive scan of part2 (replaces scanB2 dispatch)
        int v = (t < NB2) ? part2[t] : 0;
        int inc = wave_incl_scan(v, lane);
        if (lane == 63) wsum[wv] = inc;
        __syncthreads();
        if (t == 0) {
            int a = 0;
            for (int k = 0; k < 8; k++) { int x = wsum[k]; wsum[k] = a; a += x; }
        }
        __syncthreads();
        p2s[t] = wsum[wv] + inc - v;
        __syncthreads();
    }
    int f0 = b * GB1;
    int base = offs[f0] + p2s[f0 >> 8];
    int nxt;
    if (b == NBKT - 1) nxt = N_EDGES;
    else { int f1 = (b + 1) * GB1; nxt = offs[f1] + p2s[f1 >> 8]; }
    int nb = nxt - base;
    if (nb > DCAP) nb = DCAP;  // statistically impossible; guards LDS OOB
    for (int i = t; i < SEGB; i += 512) hist[i] = 0;
    __syncthreads();
    for (int i = t; i < nb; i += 512) {
        unsigned v = ebuf[base + i];
        eb[i] = v;
        int bin = (int)((v >> 16) << 3) | (int)((v & 0xFFFFu) >> 13);
        atomicAdd(&hist[bin], 1);
    }
    __syncthreads();
    int b0 = t << 2;
    int loc0 = hist[b0], loc1 = hist[b0 + 1], loc2 = hist[b0 + 2], loc3 = hist[b0 + 3];
    int s = loc0 + loc1 + loc2 + loc3;
    int inc = wave_incl_scan(s, lane);
    if (lane == 63) wsum[wv] = inc;
    __syncthreads();
    if (t == 0) {
        int a = 0;
        for (int k = 0; k < 8; k++) { int x = wsum[k]; wsum[k] = a; a += x; }
    }
    __syncthreads();
    int run = wsum[wv] + inc - s;
    hist[b0] = run; run += loc0;
    hist[b0 + 1] = run; run += loc1;
    hist[b0 + 2] = run; run += loc2;
    hist[b0 + 3] = run;
    __syncthreads();
    if (t < 256) {
        int node = b * 256 + t;
        if (node < N_NODES) rowptr[node] = base + hist[t << 3];
    }
    if (b == 0 && t == 0) rowptr[N_NODES] = N_EDGES;
    __syncthreads();
    for (int i = t; i < nb; i += 512) {
        unsigned v = eb[i];
        int bin = (int)((v >> 16) << 3) | (int)((v & 0xFFFFu) >> 13);
        int r = atomicAdd(&hist[bin], 1);
        csr[base + r] = (unsigned short)(v & 0xFFFFu);
    }
}

// ------------------------------------------------------------- aggregation
// PAIRED-NODE wave: each wave owns nodes n and n+NHALF with fully
// interleaved instruction streams (8 csr + 8 h-gather + 8 es loads issued
// per iteration) -> 2 independent dependency chains per wave, 2x in-flight
// lines, half the waves/blocks. All batches masked 32-wide (replaces the
// 16/8 remainder; regroups the fp sum only). Lane L: g=L>>3 edge slot,
// o=L&7 head (16 B of the 128 B h row; 8 line-requests per gather instr).
__global__ __launch_bounds__(256) void agg_kernel(
    const uint4* __restrict__ h8, const float* __restrict__ es,
    const float* __restrict__ ed, const int* __restrict__ rowptr,
    const unsigned short* __restrict__ csr, const float4* __restrict__ b4,
    float4* __restrict__ out4, int apply_elu) {
    int t = threadIdx.x;
    int wv = t >> 6, L = t & 63;
    int w = blockIdx.x * 4 + wv;
    if (w >= NHALF) return;
    int nA = w, nB = w + NHALF;
    int g = L >> 3, o = L & 7;
    int begA = rowptr[nA], endA = rowptr[nA + 1];
    int begB = rowptr[nB], endB = rowptr[nB + 1];
    float ednA = ed[nA * NH + o];
    float ednB = ed[nB * NH + o];
    int lastA = (endA > begA) ? (endA - 1) : 0;
    int lastB = (endB > begB) ? (endB - 1) : 0;
    int itA = (endA - begA + 31) >> 5;
    int itB = (endB - begB + 31) >> 5;
    int iters = (itA > itB) ? itA : itB;  // wave-uniform
    float accA[8] = {0.f, 0.f, 0.f, 0.f, 0.f, 0.f, 0.f, 0.f};
    float accB[8] = {0.f, 0.f, 0.f, 0.f, 0.f, 0.f, 0.f, 0.f};
    float ssA = 0.f, ssB = 0.f;
    for (int k = 0; k < iters; k++) {
        int jA = begA + (k << 5) + g;
        int jB = begB + (k << 5) + g;
        int iA0 = jA,      iA1 = jA + 8,  iA2 = jA + 16, iA3 = jA + 24;
        int iB0 = jB,      iB1 = jB + 8,  iB2 = jB + 16, iB3 = jB + 24;
        int sA0 = csr[(iA0 < endA) ? iA0 : lastA];
        int sA1 = csr[(iA1 < endA) ? iA1 : lastA];
        int sA2 = csr[(iA2 < endA) ? iA2 : lastA];
        int sA3 = csr[(iA3 < endA) ? iA3 : lastA];
        int sB0 = csr[(iB0 < endB) ? iB0 : lastB];
        int sB1 = csr[(iB1 < endB) ? iB1 : lastB];
        int sB2 = csr[(iB2 < endB) ? iB2 : lastB];
        int sB3 = csr[(iB3 < endB) ? iB3 : lastB];
        uint4 hA0 = h8[sA0 * 8 + o];
        uint4 hA1 = h8[sA1 * 8 + o];
        uint4 hA2 = h8[sA2 * 8 + o];
        uint4 hA3 = h8[sA3 * 8 + o];
        uint4 hB0 = h8[sB0 * 8 + o];
        uint4 hB1 = h8[sB1 * 8 + o];
        uint4 hB2 = h8[sB2 * 8 + o];
        uint4 hB3 = h8[sB3 * 8 + o];
        float evA0 = es[sA0 * NH + o];
        float evA1 = es[sA1 * NH + o];
        float evA2 = es[sA2 * NH + o];
        float evA3 = es[sA3 * NH + o];
        float evB0 = es[sB0 * NH + o];
        float evB1 = es[sB1 * NH + o];
        float evB2 = es[sB2 * NH + o];
        float evB3 = es[sB3 * NH + o];
        float eA0 = evA0 + ednA; eA0 = (eA0 > 0.f) ? eA0 : 0.2f * eA0;
        float eA1 = evA1 + ednA; eA1 = (eA1 > 0.f) ? eA1 : 0.2f * eA1;
        float eA2 = evA2 + ednA; eA2 = (eA2 > 0.f) ? eA2 : 0.2f * eA2;
        float eA3 = evA3 + ednA; eA3 = (eA3 > 0.f) ? eA3 : 0.2f * eA3;
        float eB0 = evB0 + ednB; eB0 = (eB0 > 0.f) ? eB0 : 0.2f * eB0;
        float eB1 = evB1 + ednB; eB1 = (eB1 > 0.f) ? eB1 : 0.2f * eB1;
        float eB2 = evB2 + ednB; eB2 = (eB2 > 0.f) ? eB2 : 0.2f * eB2;
        float eB3 = evB3 + ednB; eB3 = (eB3 > 0.f) ? eB3 : 0.2f * eB3;
        float wA0 = (iA0 < endA) ? __expf(eA0) : 0.f;
        float wA1 = (iA1 < endA) ? __expf(eA1) : 0.f;
        float wA2 = (iA2 < endA) ? __expf(eA2) : 0.f;
        float wA3 = (iA3 < endA) ? __expf(eA3) : 0.f;
        float wB0 = (iB0 < endB) ? __expf(eB0) : 0.f;
        float wB1 = (iB1 < endB) ? __expf(eB1) : 0.f;
        float wB2 = (iB2 < endB) ? __expf(eB2) : 0.f;
        float wB3 = (iB3 < endB) ? __expf(eB3) : 0.f;
        union { uint4 u; _Float16 f[8]; } cA0, cA1, cA2, cA3, cB0, cB1, cB2, cB3;
        cA0.u = hA0; cA1.u = hA1; cA2.u = hA2; cA3.u = hA3;
        cB0.u = hB0; cB1.u = hB1; cB2.u = hB2; cB3.u = hB3;
#pragma unroll
        for (int i = 0; i < 8; i++) {
            accA[i] += wA0 * (float)cA0.f[i] + wA1 * (float)cA1.f[i];
            accA[i] += wA2 * (float)cA2.f[i] + wA3 * (float)cA3.f[i];
            accB[i] += wB0 * (float)cB0.f[i] + wB1 * (float)cB1.f[i];
            accB[i] += wB2 * (float)cB2.f[i] + wB3 * (float)cB3.f[i];
        }
        ssA += wA0 + wA1; ssA += wA2 + wA3;
        ssB += wB0 + wB1; ssB += wB2 + wB3;
    }
#pragma unroll
    for (int i = 0; i < 8; i++) {
        accA[i] += __shfl_xor(accA[i], 8);
        accA[i] += __shfl_xor(accA[i], 16);
        accA[i] += __shfl_xor(accA[i], 32);
        accB[i] += __shfl_xor(accB[i], 8);
        accB[i] += __shfl_xor(accB[i], 16);
        accB[i] += __shfl_xor(accB[i], 32);
    }
    ssA += __shfl_xor(ssA, 8);
    ssA += __shfl_xor(ssA, 16);
    ssA += __shfl_xor(ssA, 32);
    ssB += __shfl_xor(ssB, 8);
    ssB += __shfl_xor(ssB, 16);
    ssB += __shfl_xor(ssB, 32);

    if (g == 0) {
        float4 bv0 = b4[2 * o], bv1 = b4[2 * o + 1];
        {
            float inv = 1.f / (ssA + 1e-16f);
            float4 r0, r1;
            r0.x = accA[0] * inv + bv0.x; r0.y = accA[1] * inv + bv0.y;
            r0.z = accA[2] * inv + bv0.z; r0.w = accA[3] * inv + bv0.w;
            r1.x = accA[4] * inv + bv1.x; r1.y = accA[5] * inv + bv1.y;
            r1.z = accA[6] * inv + bv1.z; r1.w = accA[7] * inv + bv1.w;
            if (apply_elu) {
                r0.x = (r0.x > 0.f) ? r0.x : (__expf(r0.x) - 1.f);
                r0.y = (r0.y > 0.f) ? r0.y : (__expf(r0.y) - 1.f);
                r0.z = (r0.z > 0.f) ? r0.z : (__expf(r0.z) - 1.f);
                r0.w = (r0.w > 0.f) ? r0.w : (__expf(r0.w) - 1.f);
                r1.x = (r1.x > 0.f) ? r1.x : (__expf(r1.x) - 1.f);
                r1.y = (r1.y > 0.f) ? r1.y : (__expf(r1.y) - 1.f);
                r1.z = (r1.z > 0.f) ? r1.z : (__expf(r1.z) - 1.f);
                r1.w = (r1.w > 0.f) ? r1.w : (__expf(r1.w) - 1.f);
            }
            out4[nA * 16 + 2 * o] = r0;
            out4[nA * 16 + 2 * o + 1] = r1;
        }
        {
            float inv = 1.f / (ssB + 1e-16f);
            float4 r0, r1;
            r0.x = accB[0] * inv + bv0.x; r0.y = accB[1] * inv + bv0.y;
            r0.z = accB[2] * inv + bv0.z; r0.w = accB[3] * inv + bv0.w;
            r1.x = accB[4] * inv + bv1.x; r1.y = accB[5] * inv + bv1.y;
            r1.z = accB[6] * inv + bv1.z; r1.w = accB[7] * inv + bv1.w;
            if (apply_elu) {
                r0.x = (r0.x > 0.f) ? r0.x : (__expf(r0.x) - 1.f);
                r0.y = (r0.y > 0.f) ? r0.y : (__expf(r0.y) - 1.f);
                r0.z = (r0.z > 0.f) ? r0.z : (__expf(r0.z) - 1.f);
                r0.w = (r0.w > 0.f) ? r0.w : (__expf(r0.w) - 1.f);
                r1.x = (r1.x > 0.f) ? r1.x : (__expf(r1.x) - 1.f);
                r1.y = (r1.y > 0.f) ? r1.y : (__expf(r1.y) - 1.f);
                r1.z = (r1.z > 0.f) ? r1.z : (__expf(r1.z) - 1.f);
                r1.w = (r1.w > 0.f) ? r1.w : (__expf(r1.w) - 1.f);
            }
            out4[nB * 16 + 2 * o] = r0;
            out4[nB * 16 + 2 * o + 1] = r1;
        }
    }
}

// ---------------------------------------------------------------- launcher
extern "C" void kernel_launch(void* const* d_in, const int* in_sizes, int n_in,
                              void* d_out, int out_size, void* d_ws, size_t ws_size,
                              hipStream_t stream) {
    const float* x   = (const float*)d_in[0];
    const int*   ei  = (const int*)d_in[1];
    const int*   src = ei;
    const int*   dst = ei + N_EDGES;
    const float* W[4]   = {(const float*)d_in[2], (const float*)d_in[5],
                           (const float*)d_in[8], (const float*)d_in[11]};
    const float* att[4] = {(const float*)d_in[3], (const float*)d_in[6],
                           (const float*)d_in[9], (const float*)d_in[12]};
    const float* bb[4]  = {(const float*)d_in[4], (const float*)d_in[7],
                           (const float*)d_in[10], (const float*)d_in[13]};

    char* wsb = (char*)d_ws;
    size_t off = 0;
    auto alloc = [&](size_t bytes) -> void* {
        size_t a = (off + 255) & ~(size_t)255;
        off = a + bytes;
        return (void*)(wsb + a);
    };
    int*            offs   = (int*)alloc((size_t)SCAN_M * 4);
    int*            part2  = (int*)alloc((size_t)NB2 * 4);
    unsigned*       ebuf   = (unsigned*)alloc((size_t)N_EDGES * 4);
    int*            rowptr = (int*)alloc((size_t)(N_NODES + 1) * 4);
    unsigned short* csr    = (unsigned short*)alloc((size_t)N_EDGES * 2);
    _Float16*       h      = (_Float16*)alloc((size_t)N_NODES * HD * 2);
    float*          es     = (float*)alloc((size_t)N_NODES * NH * 4);
    float*          ed     = (float*)alloc((size_t)N_NODES * NH * 4);
    float*          act0   = (float*)alloc((size_t)N_NODES * HD * 4);
    float*          act1   = (float*)alloc((size_t)N_NODES * HD * 4);

    const int GA = (NHALF + 3) / 4;  // 6250 blocks, wave = 2 nodes
    const dim3 GG(GBN, 4);           // 4 y-blocks x 16 features
    const dim3 GF(GBN, 5);           // y<4: gemm layer0, y==4: histA

    // CSR build + layer-0 GEMM fused (independent work overlapped)
    histA_gemm_kernel<<<GF, 256, 0, stream>>>(dst, offs, x, W[0], att[0],
                                              h, es, ed);
    scanB1_kernel<<<NB2, 256, 0, stream>>>(offs, part2);
    scatC_kernel<<<GB1, 256, 0, stream>>>(src, dst, offs, part2, ebuf);
    csrD_kernel<<<NBKT, 512, 0, stream>>>(offs, part2, ebuf, rowptr, csr);

    agg_kernel<<<GA, 256, 0, stream>>>((const uint4*)h, es, ed, rowptr, csr,
                                       (const float4*)bb[0], (float4*)act0, 1);
    gemm_att_kernel<64><<<GG, 256, 0, stream>>>(act0, W[1], att[1], h, es, ed);
    agg_kernel<<<GA, 256, 0, stream>>>((const uint4*)h, es, ed, rowptr, csr,
                                       (const float4*)bb[1], (float4*)act1, 1);
    gemm_att_kernel<64><<<GG, 256, 0, stream>>>(act1, W[2], att[2], h, es, ed);
    agg_kernel<<<GA, 256, 0, stream>>>((const uint4*)h, es, ed, rowptr, csr,
                                       (const float4*)bb[2], (float4*)act0, 1);
    gemm_att_kernel<64><<<GG, 256, 0, stream>>>(act0, W[3], att[3], h, es, ed);
    agg_kernel<<<GA, 256, 0, stream>>>((const uint4*)h, es, ed, rowptr, csr,
                                       (const float4*)bb[3], (float4*)d_out, 0);
}

// Round 5
// 335.112 us; speedup vs baseline: 1.0917x; 1.0917x over previous
//
#include <hip/hip_runtime.h>

#define N_NODES 50000
#define N_EDGES 1600000
#define HD 64    // H*D
#define NH 8     // heads
#define NBKT 196 // dst buckets (dst >> 8)
#define EPB 8192 // edges per block in binning passes
#define GB1 196  // ceil(N_EDGES / EPB)
#define SCAN_M (NBKT * GB1)   // 38416
#define NB2 151               // ceil(SCAN_M / 256)
#define DCAP 8960             // pass-D LDS edge capacity (mean 8192, +8.5 sigma)
#define SEGB 2048             // 256 dst-low bins x 8 src segments
#define GBN 196               // ceil(N_NODES / 256) node blocks for gemm

__device__ inline int wave_incl_scan(int v, int lane) {
#pragma unroll
    for (int o = 1; o < 64; o <<= 1) {
        int t = __shfl_up(v, o);
        if (lane >= o) v += t;
    }
    return v;
}

// ------------------------------------------------- GEMM + attention logits
// PROVEN config: thread = node, 16 output features (= 2 complete heads),
// 4 y-blocks. x re-reads are L3-absorbed; narrow tile keeps VGPR/SGPR
// pressure low -> deep load pipelining. 32/64-wide measured SLOWER.
template <int F>
__device__ __forceinline__ void gemm_body16(
    int bx, int by, int t,
    const float* __restrict__ x, const float* __restrict__ W,
    const float* __restrict__ att,
    _Float16* __restrict__ h, float* __restrict__ es, float* __restrict__ ed) {
    int n = bx * 256 + t;
    int f0 = by * 16;
    int nc = (n < N_NODES) ? n : (N_NODES - 1);
    const float4* xrow = (const float4*)x + (size_t)nc * (F / 4);
    float acc[16];
#pragma unroll
    for (int i = 0; i < 16; i++) acc[i] = 0.f;
#pragma unroll 4
    for (int kk = 0; kk < F / 4; kk++) {
        float4 xv = xrow[kk];
        const float* Wk = W + (kk * 4) * 64 + f0;  // wave-uniform base
#pragma unroll
        for (int i = 0; i < 16; i++)
            acc[i] += xv.x * Wk[i] + xv.y * Wk[64 + i] +
                      xv.z * Wk[128 + i] + xv.w * Wk[192 + i];
    }
    if (n >= N_NODES) return;

    float s0 = 0.f, s1 = 0.f, d0 = 0.f, d1 = 0.f;
#pragma unroll
    for (int i = 0; i < 8; i++) {
        s0 += acc[i] * att[f0 + i];
        d0 += acc[i] * att[64 + f0 + i];
    }
#pragma unroll
    for (int i = 8; i < 16; i++) {
        s1 += acc[i] * att[f0 + i];
        d1 += acc[i] * att[64 + f0 + i];
    }
    int hh = f0 >> 3;
    es[n * NH + hh] = s0; es[n * NH + hh + 1] = s1;
    ed[n * NH + hh] = d0; ed[n * NH + hh + 1] = d1;

    union { _Float16 hf[16]; uint4 u[2]; } cv;
#pragma unroll
    for (int i = 0; i < 16; i++) cv.hf[i] = (_Float16)acc[i];
    uint4* hp = (uint4*)(h + (size_t)n * HD + f0);
    hp[0] = cv.u[0];
    hp[1] = cv.u[1];
}

template <int F>
__global__ __launch_bounds__(256) void gemm_att_kernel(
    const float* __restrict__ x, const float* __restrict__ W,
    const float* __restrict__ att,
    _Float16* __restrict__ h, float* __restrict__ es, float* __restrict__ ed) {
    gemm_body16<F>(blockIdx.x, blockIdx.y, threadIdx.x, x, W, att, h, es, ed);
}

// ---------------------------------------------------- CSR build (no global atomics)
// Fused: grid (GBN, 5). y<4 -> gemm layer0 y-block (hides histA); y==4 ->
// dst histogram block (GB1 == GBN == 196).
__global__ __launch_bounds__(256) void histA_gemm_kernel(
    const int* __restrict__ dst, int* __restrict__ offs,
    const float* __restrict__ x, const float* __restrict__ W,
    const float* __restrict__ att,
    _Float16* __restrict__ h, float* __restrict__ es, float* __restrict__ ed) {
    if (blockIdx.y < 4) {
        gemm_body16<128>(blockIdx.x, blockIdx.y, threadIdx.x, x, W, att, h, es, ed);
        return;
    }
    int bb = blockIdx.x;
    __shared__ int hist[NBKT];
    int t = threadIdx.x;
    if (t < NBKT) hist[t] = 0;
    __syncthreads();
    int base = bb * EPB;
#pragma unroll
    for (int k = 0; k < EPB / 256; k++) {
        int e = base + k * 256 + t;
        if (e < N_EDGES) atomicAdd(&hist[dst[e] >> 8], 1);
    }
    __syncthreads();
    if (t < NBKT) offs[t * GB1 + bb] = hist[t];
}

__global__ __launch_bounds__(256) void scanB1_kernel(int* __restrict__ offs,
                                                     int* __restrict__ part2) {
    __shared__ int wsum[4];
    int t = threadIdx.x, lane = t & 63, wv = t >> 6;
    int i = blockIdx.x * 256 + t;
    int v = (i < SCAN_M) ? offs[i] : 0;
    int inc = wave_incl_scan(v, lane);
    if (lane == 63) wsum[wv] = inc;
    __syncthreads();
    if (t == 0) {
        int a = 0;
        for (int k = 0; k < 4; k++) { int x = wsum[k]; wsum[k] = a; a += x; }
    }
    __syncthreads();
    int excl = wsum[wv] + inc - v;
    if (i < SCAN_M) offs[i] = excl;
    if (t == 255) part2[blockIdx.x] = wsum[wv] + inc;
}

// scanB2 folded into consumers: each block exclusive-scans part2 (151 ints) in LDS.
__global__ __launch_bounds__(256) void scatC_kernel(const int* __restrict__ src,
                                                    const int* __restrict__ dst,
                                                    const int* __restrict__ offs,
                                                    const int* __restrict__ part2,
                                                    unsigned* __restrict__ ebuf) {
    __shared__ int cur[NBKT];
    __shared__ int base_s[NBKT];
    __shared__ int p2s[256];
    __shared__ int p2w[4];
    int t = threadIdx.x, lane = t & 63, wv = t >> 6;
    int v = (t < NB2) ? part2[t] : 0;
    int inc = wave_incl_scan(v, lane);
    if (lane == 63) p2w[wv] = inc;
    __syncthreads();
    if (t == 0) {
        int a = 0;
        for (int k = 0; k < 4; k++) { int x = p2w[k]; p2w[k] = a; a += x; }
    }
    __syncthreads();
    p2s[t] = p2w[wv] + inc - v;
    if (t < NBKT) cur[t] = 0;
    __syncthreads();
    if (t < NBKT) {
        int f = t * GB1 + blockIdx.x;
        base_s[t] = offs[f] + p2s[f >> 8];
    }
    __syncthreads();
    int base = blockIdx.x * EPB;
#pragma unroll
    for (int k = 0; k < EPB / 256; k++) {
        int e = base + k * 256 + t;
        if (e < N_EDGES) {
            int d = dst[e];
            int b = d >> 8;
            int r = atomicAdd(&cur[b], 1);
            ebuf[base_s[b] + r] = (unsigned)src[e] | ((unsigned)(d & 255) << 16);
        }
    }
}

__global__ __launch_bounds__(512) void csrD_kernel(const int* __restrict__ offs,
                                                   const int* __restrict__ part2,
                                                   const unsigned* __restrict__ ebuf,
                                                   int* __restrict__ rowptr,
                                                   unsigned short* __restrict__ csr) {
    __shared__ unsigned eb[DCAP];
    __shared__ int hist[SEGB];
    __shared__ int wsum[8];
    __shared__ int p2s[512];
    int b = blockIdx.x, t = threadIdx.x;
    int lane = t & 63, wv = t >> 6;
    {   // in-block exclusive scan of part2 (replaces scanB2 dispatch)
        int v = (t < NB2) ? part2[t] : 0;
        int inc = wave_incl_scan(v, lane);
        if (lane == 63) wsum[wv] = inc;
        __syncthreads();
        if (t == 0) {
            int a = 0;
            for (int k = 0; k < 8; k++) { int x = wsum[k]; wsum[k] = a; a += x; }
        }
        __syncthreads();
        p2s[t] = wsum[wv] + inc - v;
        __syncthreads();
    }
    int f0 = b * GB1;
    int base = offs[f0] + p2s[f0 >> 8];
    int nxt;
    if (b == NBKT - 1) nxt = N_EDGES;
    else { int f1 = (b + 1) * GB1; nxt = offs[f1] + p2s[f1 >> 8]; }
    int nb = nxt - base;
    if (nb > DCAP) nb = DCAP;  // statistically impossible; guards LDS OOB
    for (int i = t; i < SEGB; i += 512) hist[i] = 0;
    __syncthreads();
    for (int i = t; i < nb; i += 512) {
        unsigned v = ebuf[base + i];
        eb[i] = v;
        int bin = (int)((v >> 16) << 3) | (int)((v & 0xFFFFu) >> 13);
        atomicAdd(&hist[bin], 1);
    }
    __syncthreads();
    int b0 = t << 2;
    int loc0 = hist[b0], loc1 = hist[b0 + 1], loc2 = hist[b0 + 2], loc3 = hist[b0 + 3];
    int s = loc0 + loc1 + loc2 + loc3;
    int inc = wave_incl_scan(s, lane);
    if (lane == 63) wsum[wv] = inc;
    __syncthreads();
    if (t == 0) {
        int a = 0;
        for (int k = 0; k < 8; k++) { int x = wsum[k]; wsum[k] = a; a += x; }
    }
    __syncthreads();
    int run = wsum[wv] + inc - s;
    hist[b0] = run; run += loc0;
    hist[b0 + 1] = run; run += loc1;
    hist[b0 + 2] = run; run += loc2;
    hist[b0 + 3] = run;
    __syncthreads();
    if (t < 256) {
        int node = b * 256 + t;
        if (node < N_NODES) rowptr[node] = base + hist[t << 3];
    }
    if (b == 0 && t == 0) rowptr[N_NODES] = N_EDGES;
    __syncthreads();
    for (int i = t; i < nb; i += 512) {
        unsigned v = eb[i];
        int bin = (int)((v >> 16) << 3) | (int)((v & 0xFFFFu) >> 13);
        int r = atomicAdd(&hist[bin], 1);
        csr[base + r] = (unsigned short)(v & 0xFFFFu);
    }
}

// ------------------------------------------------------------- aggregation
// SPLIT-WAVE: each HALF-WAVE (32 lanes = 4 edge slots x 8 heads) owns one
// node with its OWN exact trip count (beg/end uniform per half; divergence
// between halves is exec-masked, short half issues no memory requests).
// vs round-4 max()-paired masking: work inflation 1.72x -> 1.25x while
// keeping 2 nodes/wave and 32 h-lines in flight per iteration. Bulk =
// exact 16-edge batches; remainder = one masked 16-batch. Reduction: 2
// shuffles (xor 8,16) within the half. 8 nodes per 256-thread block;
// 6250 x 8 = 50000 exactly (no partial block).
__global__ __launch_bounds__(256) void agg_kernel(
    const uint4* __restrict__ h8, const float* __restrict__ es,
    const float* __restrict__ ed, const int* __restrict__ rowptr,
    const unsigned short* __restrict__ csr, const float4* __restrict__ b4,
    float4* __restrict__ out4, int apply_elu) {
    int t = threadIdx.x;
    int wv = t >> 6, L = t & 63;
    int n = blockIdx.x * 8 + wv * 2 + (L >> 5);
    int g = (L >> 3) & 3, o = L & 7;
    int beg = rowptr[n], end = rowptr[n + 1];
    float edn = ed[n * NH + o];
    int last = (end > beg) ? (end - 1) : 0;
    float acc[8] = {0.f, 0.f, 0.f, 0.f, 0.f, 0.f, 0.f, 0.f};
    float ssum = 0.f;
    int j = beg;
    for (; j + 16 <= end; j += 16) {   // exact bulk (uniform per half-wave)
        int s0 = csr[j + g];
        int s1 = csr[j + 4 + g];
        int s2 = csr[j + 8 + g];
        int s3 = csr[j + 12 + g];
        uint4 hv0 = h8[s0 * 8 + o];
        uint4 hv1 = h8[s1 * 8 + o];
        uint4 hv2 = h8[s2 * 8 + o];
        uint4 hv3 = h8[s3 * 8 + o];
        float ev0 = es[s0 * NH + o];
        float ev1 = es[s1 * NH + o];
        float ev2 = es[s2 * NH + o];
        float ev3 = es[s3 * NH + o];
        float e0 = ev0 + edn; e0 = (e0 > 0.f) ? e0 : 0.2f * e0;
        float e1 = ev1 + edn; e1 = (e1 > 0.f) ? e1 : 0.2f * e1;
        float e2 = ev2 + edn; e2 = (e2 > 0.f) ? e2 : 0.2f * e2;
        float e3 = ev3 + edn; e3 = (e3 > 0.f) ? e3 : 0.2f * e3;
        float w0 = __expf(e0), w1 = __expf(e1);
        float w2 = __expf(e2), w3 = __expf(e3);
        union { uint4 u; _Float16 f[8]; } c0, c1, c2, c3;
        c0.u = hv0; c1.u = hv1; c2.u = hv2; c3.u = hv3;
#pragma unroll
        for (int i = 0; i < 8; i++) {
            acc[i] += w0 * (float)c0.f[i] + w1 * (float)c1.f[i];
            acc[i] += w2 * (float)c2.f[i] + w3 * (float)c3.f[i];
        }
        ssum += w0 + w1;
        ssum += w2 + w3;
    }
    if (j < end) {                     // one masked 16-batch (remainder < 16)
        int i0 = j + g, i1 = j + 4 + g, i2 = j + 8 + g, i3 = j + 12 + g;
        int s0 = csr[(i0 < end) ? i0 : last];
        int s1 = csr[(i1 < end) ? i1 : last];
        int s2 = csr[(i2 < end) ? i2 : last];
        int s3 = csr[(i3 < end) ? i3 : last];
        uint4 hv0 = h8[s0 * 8 + o];
        uint4 hv1 = h8[s1 * 8 + o];
        uint4 hv2 = h8[s2 * 8 + o];
        uint4 hv3 = h8[s3 * 8 + o];
        float ev0 = es[s0 * NH + o];
        float ev1 = es[s1 * NH + o];
        float ev2 = es[s2 * NH + o];
        float ev3 = es[s3 * NH + o];
        float e0 = ev0 + edn; e0 = (e0 > 0.f) ? e0 : 0.2f * e0;
        float e1 = ev1 + edn; e1 = (e1 > 0.f) ? e1 : 0.2f * e1;
        float e2 = ev2 + edn; e2 = (e2 > 0.f) ? e2 : 0.2f * e2;
        float e3 = ev3 + edn; e3 = (e3 > 0.f) ? e3 : 0.2f * e3;
        float w0 = (i0 < end) ? __expf(e0) : 0.f;
        float w1 = (i1 < end) ? __expf(e1) : 0.f;
        float w2 = (i2 < end) ? __expf(e2) : 0.f;
        float w3 = (i3 < end) ? __expf(e3) : 0.f;
        union { uint4 u; _Float16 f[8]; } c0, c1, c2, c3;
        c0.u = hv0; c1.u = hv1; c2.u = hv2; c3.u = hv3;
#pragma unroll
        for (int i = 0; i < 8; i++) {
            acc[i] += w0 * (float)c0.f[i] + w1 * (float)c1.f[i];
            acc[i] += w2 * (float)c2.f[i] + w3 * (float)c3.f[i];
        }
        ssum += w0 + w1;
        ssum += w2 + w3;
    }
#pragma unroll
    for (int i = 0; i < 8; i++) {      // reduce 4 slots within the half-wave
        acc[i] += __shfl_xor(acc[i], 8);
        acc[i] += __shfl_xor(acc[i], 16);
    }
    ssum += __shfl_xor(ssum, 8);
    ssum += __shfl_xor(ssum, 16);

    if (g == 0) {                      // lanes 0-7 (node A) and 32-39 (node B)
        float inv = 1.f / (ssum + 1e-16f);
        float4 bv0 = b4[2 * o], bv1 = b4[2 * o + 1];
        float4 r0, r1;
        r0.x = acc[0] * inv + bv0.x; r0.y = acc[1] * inv + bv0.y;
        r0.z = acc[2] * inv + bv0.z; r0.w = acc[3] * inv + bv0.w;
        r1.x = acc[4] * inv + bv1.x; r1.y = acc[5] * inv + bv1.y;
        r1.z = acc[6] * inv + bv1.z; r1.w = acc[7] * inv + bv1.w;
        if (apply_elu) {
            r0.x = (r0.x > 0.f) ? r0.x : (__expf(r0.x) - 1.f);
            r0.y = (r0.y > 0.f) ? r0.y : (__expf(r0.y) - 1.f);
            r0.z = (r0.z > 0.f) ? r0.z : (__expf(r0.z) - 1.f);
            r0.w = (r0.w > 0.f) ? r0.w : (__expf(r0.w) - 1.f);
            r1.x = (r1.x > 0.f) ? r1.x : (__expf(r1.x) - 1.f);
            r1.y = (r1.y > 0.f) ? r1.y : (__expf(r1.y) - 1.f);
            r1.z = (r1.z > 0.f) ? r1.z : (__expf(r1.z) - 1.f);
            r1.w = (r1.w > 0.f) ? r1.w : (__expf(r1.w) - 1.f);
        }
        out4[n * 16 + 2 * o] = r0;
        out4[n * 16 + 2 * o + 1] = r1;
    }
}

// ---------------------------------------------------------------- launcher
extern "C" void kernel_launch(void* const* d_in, const int* in_sizes, int n_in,
                              void* d_out, int out_size, void* d_ws, size_t ws_size,
                              hipStream_t stream) {
    const float* x   = (const float*)d_in[0];
    const int*   ei  = (const int*)d_in[1];
    const int*   src = ei;
    const int*   dst = ei + N_EDGES;
    const float* W[4]   = {(const float*)d_in[2], (const float*)d_in[5],
                           (const float*)d_in[8], (const float*)d_in[11]};
    const float* att[4] = {(const float*)d_in[3], (const float*)d_in[6],
                           (const float*)d_in[9], (const float*)d_in[12]};
    const float* bb[4]  = {(const float*)d_in[4], (const float*)d_in[7],
                           (const float*)d_in[10], (const float*)d_in[13]};

    char* wsb = (char*)d_ws;
    size_t off = 0;
    auto alloc = [&](size_t bytes) -> void* {
        size_t a = (off + 255) & ~(size_t)255;
        off = a + bytes;
        return (void*)(wsb + a);
    };
    int*            offs   = (int*)alloc((size_t)SCAN_M * 4);
    int*            part2  = (int*)alloc((size_t)NB2 * 4);
    unsigned*       ebuf   = (unsigned*)alloc((size_t)N_EDGES * 4);
    int*            rowptr = (int*)alloc((size_t)(N_NODES + 1) * 4);
    unsigned short* csr    = (unsigned short*)alloc((size_t)N_EDGES * 2);
    _Float16*       h      = (_Float16*)alloc((size_t)N_NODES * HD * 2);
    float*          es     = (float*)alloc((size_t)N_NODES * NH * 4);
    float*          ed     = (float*)alloc((size_t)N_NODES * NH * 4);
    float*          act0   = (float*)alloc((size_t)N_NODES * HD * 4);
    float*          act1   = (float*)alloc((size_t)N_NODES * HD * 4);

    const int GA = N_NODES / 8;  // 6250 blocks, 8 nodes per block
    const dim3 GG(GBN, 4);       // 4 y-blocks x 16 features
    const dim3 GF(GBN, 5);       // y<4: gemm layer0, y==4: histA

    // CSR build + layer-0 GEMM fused (independent work overlapped)
    histA_gemm_kernel<<<GF, 256, 0, stream>>>(dst, offs, x, W[0], att[0],
                                              h, es, ed);
    scanB1_kernel<<<NB2, 256, 0, stream>>>(offs, part2);
    scatC_kernel<<<GB1, 256, 0, stream>>>(src, dst, offs, part2, ebuf);
    csrD_kernel<<<NBKT, 512, 0, stream>>>(offs, part2, ebuf, rowptr, csr);

    agg_kernel<<<GA, 256, 0, stream>>>((const uint4*)h, es, ed, rowptr, csr,
                                       (const float4*)bb[0], (float4*)act0, 1);
    gemm_att_kernel<64><<<GG, 256, 0, stream>>>(act0, W[1], att[1], h, es, ed);
    agg_kernel<<<GA, 256, 0, stream>>>((const uint4*)h, es, ed, rowptr, csr,
                                       (const float4*)bb[1], (float4*)act1, 1);
    gemm_att_kernel<64><<<GG, 256, 0, stream>>>(act1, W[2], att[2], h, es, ed);
    agg_kernel<<<GA, 256, 0, stream>>>((const uint4*)h, es, ed, rowptr, csr,
                                       (const float4*)bb[2], (float4*)act0, 1);
    gemm_att_kernel<64><<<GG, 256, 0, stream>>>(act0, W[3], att[3], h, es, ed);
    agg_kernel<<<GA, 256, 0, stream>>>((const uint4*)h, es, ed, rowptr, csr,
                                       (const float4*)bb[3], (float4*)d_out, 0);
}

// Round 6
// 304.164 us; speedup vs baseline: 1.2028x; 1.1017x over previous
//
#include <hip/hip_runtime.h>

#define N_NODES 50000
#define N_EDGES 1600000
#define HD 64    // H*D
#define NH 8     // heads
#define NBKT 196 // dst buckets (dst >> 8)
#define EPB 8192 // edges per block in binning passes
#define GB1 196  // ceil(N_EDGES / EPB)
#define SCAN_M (NBKT * GB1)   // 38416
#define NB2 151               // ceil(SCAN_M / 256)
#define DCAP 8960             // pass-D LDS edge capacity (mean 8192, +8.5 sigma)
#define SEGB 2048             // 256 dst-low bins x 8 src segments
#define GBN 196               // ceil(N_NODES / 256) node blocks for gemm

__device__ inline int wave_incl_scan(int v, int lane) {
#pragma unroll
    for (int o = 1; o < 64; o <<= 1) {
        int t = __shfl_up(v, o);
        if (lane >= o) v += t;
    }
    return v;
}

// ------------------------------------------------- GEMM + attention logits
// PROVEN config: thread = node, 16 output features (= 2 complete heads),
// 4 y-blocks. x re-reads are L3-absorbed; narrow tile keeps VGPR/SGPR
// pressure low -> deep load pipelining. 32/64-wide measured SLOWER.
// (Only used for layer 0 now; layers 1-3 GEMMs are fused into aggemm.)
template <int F>
__device__ __forceinline__ void gemm_body16(
    int bx, int by, int t,
    const float* __restrict__ x, const float* __restrict__ W,
    const float* __restrict__ att,
    _Float16* __restrict__ h, float* __restrict__ es, float* __restrict__ ed) {
    int n = bx * 256 + t;
    int f0 = by * 16;
    int nc = (n < N_NODES) ? n : (N_NODES - 1);
    const float4* xrow = (const float4*)x + (size_t)nc * (F / 4);
    float acc[16];
#pragma unroll
    for (int i = 0; i < 16; i++) acc[i] = 0.f;
#pragma unroll 4
    for (int kk = 0; kk < F / 4; kk++) {
        float4 xv = xrow[kk];
        const float* Wk = W + (kk * 4) * 64 + f0;  // wave-uniform base
#pragma unroll
        for (int i = 0; i < 16; i++)
            acc[i] += xv.x * Wk[i] + xv.y * Wk[64 + i] +
                      xv.z * Wk[128 + i] + xv.w * Wk[192 + i];
    }
    if (n >= N_NODES) return;

    float s0 = 0.f, s1 = 0.f, d0 = 0.f, d1 = 0.f;
#pragma unroll
    for (int i = 0; i < 8; i++) {
        s0 += acc[i] * att[f0 + i];
        d0 += acc[i] * att[64 + f0 + i];
    }
#pragma unroll
    for (int i = 8; i < 16; i++) {
        s1 += acc[i] * att[f0 + i];
        d1 += acc[i] * att[64 + f0 + i];
    }
    int hh = f0 >> 3;
    es[n * NH + hh] = s0; es[n * NH + hh + 1] = s1;
    ed[n * NH + hh] = d0; ed[n * NH + hh + 1] = d1;

    union { _Float16 hf[16]; uint4 u[2]; } cv;
#pragma unroll
    for (int i = 0; i < 16; i++) cv.hf[i] = (_Float16)acc[i];
    uint4* hp = (uint4*)(h + (size_t)n * HD + f0);
    hp[0] = cv.u[0];
    hp[1] = cv.u[1];
}

// ---------------------------------------------------- CSR build (no global atomics)
// Fused: grid (GBN, 5). y<4 -> gemm layer0 y-block (hides histA); y==4 ->
// dst histogram block (GB1 == GBN == 196).
__global__ __launch_bounds__(256) void histA_gemm_kernel(
    const int* __restrict__ dst, int* __restrict__ offs,
    const float* __restrict__ x, const float* __restrict__ W,
    const float* __restrict__ att,
    _Float16* __restrict__ h, float* __restrict__ es, float* __restrict__ ed) {
    if (blockIdx.y < 4) {
        gemm_body16<128>(blockIdx.x, blockIdx.y, threadIdx.x, x, W, att, h, es, ed);
        return;
    }
    int bb = blockIdx.x;
    __shared__ int hist[NBKT];
    int t = threadIdx.x;
    if (t < NBKT) hist[t] = 0;
    __syncthreads();
    int base = bb * EPB;
#pragma unroll
    for (int k = 0; k < EPB / 256; k++) {
        int e = base + k * 256 + t;
        if (e < N_EDGES) atomicAdd(&hist[dst[e] >> 8], 1);
    }
    __syncthreads();
    if (t < NBKT) offs[t * GB1 + bb] = hist[t];
}

__global__ __launch_bounds__(256) void scanB1_kernel(int* __restrict__ offs,
                                                     int* __restrict__ part2) {
    __shared__ int wsum[4];
    int t = threadIdx.x, lane = t & 63, wv = t >> 6;
    int i = blockIdx.x * 256 + t;
    int v = (i < SCAN_M) ? offs[i] : 0;
    int inc = wave_incl_scan(v, lane);
    if (lane == 63) wsum[wv] = inc;
    __syncthreads();
    if (t == 0) {
        int a = 0;
        for (int k = 0; k < 4; k++) { int x = wsum[k]; wsum[k] = a; a += x; }
    }
    __syncthreads();
    int excl = wsum[wv] + inc - v;
    if (i < SCAN_M) offs[i] = excl;
    if (t == 255) part2[blockIdx.x] = wsum[wv] + inc;
}

// scanB2 folded into consumers: each block exclusive-scans part2 (151 ints) in LDS.
__global__ __launch_bounds__(256) void scatC_kernel(const int* __restrict__ src,
                                                    const int* __restrict__ dst,
                                                    const int* __restrict__ offs,
                                                    const int* __restrict__ part2,
                                                    unsigned* __restrict__ ebuf) {
    __shared__ int cur[NBKT];
    __shared__ int base_s[NBKT];
    __shared__ int p2s[256];
    __shared__ int p2w[4];
    int t = threadIdx.x, lane = t & 63, wv = t >> 6;
    int v = (t < NB2) ? part2[t] : 0;
    int inc = wave_incl_scan(v, lane);
    if (lane == 63) p2w[wv] = inc;
    __syncthreads();
    if (t == 0) {
        int a = 0;
        for (int k = 0; k < 4; k++) { int x = p2w[k]; p2w[k] = a; a += x; }
    }
    __syncthreads();
    p2s[t] = p2w[wv] + inc - v;
    if (t < NBKT) cur[t] = 0;
    __syncthreads();
    if (t < NBKT) {
        int f = t * GB1 + blockIdx.x;
        base_s[t] = offs[f] + p2s[f >> 8];
    }
    __syncthreads();
    int base = blockIdx.x * EPB;
#pragma unroll
    for (int k = 0; k < EPB / 256; k++) {
        int e = base + k * 256 + t;
        if (e < N_EDGES) {
            int d = dst[e];
            int b = d >> 8;
            int r = atomicAdd(&cur[b], 1);
            ebuf[base_s[b] + r] = (unsigned)src[e] | ((unsigned)(d & 255) << 16);
        }
    }
}

__global__ __launch_bounds__(512) void csrD_kernel(const int* __restrict__ offs,
                                                   const int* __restrict__ part2,
                                                   const unsigned* __restrict__ ebuf,
                                                   int* __restrict__ rowptr,
                                                   unsigned short* __restrict__ csr) {
    __shared__ unsigned eb[DCAP];
    __shared__ int hist[SEGB];
    __shared__ int wsum[8];
    __shared__ int p2s[512];
    int b = blockIdx.x, t = threadIdx.x;
    int lane = t & 63, wv = t >> 6;
    {   // in-block exclusive scan of part2 (replaces scanB2 dispatch)
        int v = (t < NB2) ? part2[t] : 0;
        int inc = wave_incl_scan(v, lane);
        if (lane == 63) wsum[wv] = inc;
        __syncthreads();
        if (t == 0) {
            int a = 0;
            for (int k = 0; k < 8; k++) { int x = wsum[k]; wsum[k] = a; a += x; }
        }
        __syncthreads();
        p2s[t] = wsum[wv] + inc - v;
        __syncthreads();
    }
    int f0 = b * GB1;
    int base = offs[f0] + p2s[f0 >> 8];
    int nxt;
    if (b == NBKT - 1) nxt = N_EDGES;
    else { int f1 = (b + 1) * GB1; nxt = offs[f1] + p2s[f1 >> 8]; }
    int nb = nxt - base;
    if (nb > DCAP) nb = DCAP;  // statistically impossible; guards LDS OOB
    for (int i = t; i < SEGB; i += 512) hist[i] = 0;
    __syncthreads();
    for (int i = t; i < nb; i += 512) {
        unsigned v = ebuf[base + i];
        eb[i] = v;
        int bin = (int)((v >> 16) << 3) | (int)((v & 0xFFFFu) >> 13);
        atomicAdd(&hist[bin], 1);
    }
    __syncthreads();
    int b0 = t << 2;
    int loc0 = hist[b0], loc1 = hist[b0 + 1], loc2 = hist[b0 + 2], loc3 = hist[b0 + 3];
    int s = loc0 + loc1 + loc2 + loc3;
    int inc = wave_incl_scan(s, lane);
    if (lane == 63) wsum[wv] = inc;
    __syncthreads();
    if (t == 0) {
        int a = 0;
        for (int k = 0; k < 8; k++) { int x = wsum[k]; wsum[k] = a; a += x; }
    }
    __syncthreads();
    int run = wsum[wv] + inc - s;
    hist[b0] = run; run += loc0;
    hist[b0 + 1] = run; run += loc1;
    hist[b0 + 2] = run; run += loc2;
    hist[b0 + 3] = run;
    __syncthreads();
    if (t < 256) {
        int node = b * 256 + t;
        if (node < N_NODES) rowptr[node] = base + hist[t << 3];
    }
    if (b == 0 && t == 0) rowptr[N_NODES] = N_EDGES;
    __syncthreads();
    for (int i = t; i < nb; i += 512) {
        unsigned v = eb[i];
        int bin = (int)((v >> 16) << 3) | (int)((v & 0xFFFFu) >> 13);
        int r = atomicAdd(&hist[bin], 1);
        csr[base + r] = (unsigned short)(v & 0xFFFFu);
    }
}

// ---------------------------------------------- agg loop (shared by both kernels)
// SPLIT-WAVE: each HALF-WAVE (32 lanes = 4 edge slots x 8 heads) owns one
// node with its OWN exact trip count. Proven round-5 structure, unchanged.
#define AGG_LOOP()                                                          \
    int beg = rowptr[n], end = rowptr[n + 1];                               \
    float edn = ed_in[n * NH + o];                                          \
    int last = (end > beg) ? (end - 1) : 0;                                 \
    float acc[8] = {0.f, 0.f, 0.f, 0.f, 0.f, 0.f, 0.f, 0.f};                \
    float ssum = 0.f;                                                       \
    int j = beg;                                                            \
    for (; j + 16 <= end; j += 16) {                                        \
        int s0 = csr[j + g];                                                \
        int s1 = csr[j + 4 + g];                                            \
        int s2 = csr[j + 8 + g];                                            \
        int s3 = csr[j + 12 + g];                                           \
        uint4 hv0 = h8[s0 * 8 + o];                                         \
        uint4 hv1 = h8[s1 * 8 + o];                                         \
        uint4 hv2 = h8[s2 * 8 + o];                                         \
        uint4 hv3 = h8[s3 * 8 + o];                                         \
        float ev0 = es_in[s0 * NH + o];                                     \
        float ev1 = es_in[s1 * NH + o];                                     \
        float ev2 = es_in[s2 * NH + o];                                     \
        float ev3 = es_in[s3 * NH + o];                                     \
        float e0 = ev0 + edn; e0 = (e0 > 0.f) ? e0 : 0.2f * e0;             \
        float e1 = ev1 + edn; e1 = (e1 > 0.f) ? e1 : 0.2f * e1;             \
        float e2 = ev2 + edn; e2 = (e2 > 0.f) ? e2 : 0.2f * e2;             \
        float e3 = ev3 + edn; e3 = (e3 > 0.f) ? e3 : 0.2f * e3;             \
        float w0 = __expf(e0), w1 = __expf(e1);                             \
        float w2 = __expf(e2), w3 = __expf(e3);                             \
        union { uint4 u; _Float16 f[8]; } c0, c1, c2, c3;                   \
        c0.u = hv0; c1.u = hv1; c2.u = hv2; c3.u = hv3;                     \
        _Pragma("unroll")                                                   \
        for (int i = 0; i < 8; i++) {                                       \
            acc[i] += w0 * (float)c0.f[i] + w1 * (float)c1.f[i];            \
            acc[i] += w2 * (float)c2.f[i] + w3 * (float)c3.f[i];            \
        }                                                                   \
        ssum += w0 + w1;                                                    \
        ssum += w2 + w3;                                                    \
    }                                                                       \
    if (j < end) {                                                          \
        int i0 = j + g, i1 = j + 4 + g, i2 = j + 8 + g, i3 = j + 12 + g;    \
        int s0 = csr[(i0 < end) ? i0 : last];                               \
        int s1 = csr[(i1 < end) ? i1 : last];                               \
        int s2 = csr[(i2 < end) ? i2 : last];                               \
        int s3 = csr[(i3 < end) ? i3 : last];                               \
        uint4 hv0 = h8[s0 * 8 + o];                                         \
        uint4 hv1 = h8[s1 * 8 + o];                                         \
        uint4 hv2 = h8[s2 * 8 + o];                                         \
        uint4 hv3 = h8[s3 * 8 + o];                                         \
        float ev0 = es_in[s0 * NH + o];                                     \
        float ev1 = es_in[s1 * NH + o];                                     \
        float ev2 = es_in[s2 * NH + o];                                     \
        float ev3 = es_in[s3 * NH + o];                                     \
        float e0 = ev0 + edn; e0 = (e0 > 0.f) ? e0 : 0.2f * e0;             \
        float e1 = ev1 + edn; e1 = (e1 > 0.f) ? e1 : 0.2f * e1;             \
        float e2 = ev2 + edn; e2 = (e2 > 0.f) ? e2 : 0.2f * e2;             \
        float e3 = ev3 + edn; e3 = (e3 > 0.f) ? e3 : 0.2f * e3;             \
        float w0 = (i0 < end) ? __expf(e0) : 0.f;                           \
        float w1 = (i1 < end) ? __expf(e1) : 0.f;                           \
        float w2 = (i2 < end) ? __expf(e2) : 0.f;                           \
        float w3 = (i3 < end) ? __expf(e3) : 0.f;                           \
        union { uint4 u; _Float16 f[8]; } c0, c1, c2, c3;                   \
        c0.u = hv0; c1.u = hv1; c2.u = hv2; c3.u = hv3;                     \
        _Pragma("unroll")                                                   \
        for (int i = 0; i < 8; i++) {                                       \
            acc[i] += w0 * (float)c0.f[i] + w1 * (float)c1.f[i];            \
            acc[i] += w2 * (float)c2.f[i] + w3 * (float)c3.f[i];            \
        }                                                                   \
        ssum += w0 + w1;                                                    \
        ssum += w2 + w3;                                                    \
    }                                                                       \
    _Pragma("unroll")                                                       \
    for (int i = 0; i < 8; i++) {                                           \
        acc[i] += __shfl_xor(acc[i], 8);                                    \
        acc[i] += __shfl_xor(acc[i], 16);                                   \
    }                                                                       \
    ssum += __shfl_xor(ssum, 8);                                            \
    ssum += __shfl_xor(ssum, 16);

// ------------------------------------------------------------- aggregation
// Final layer: plain agg -> d_out, no ELU.
__global__ __launch_bounds__(256) void agg_kernel(
    const uint4* __restrict__ h8, const float* __restrict__ es_in,
    const float* __restrict__ ed_in, const int* __restrict__ rowptr,
    const unsigned short* __restrict__ csr, const float4* __restrict__ b4,
    float4* __restrict__ out4, int apply_elu) {
    int t = threadIdx.x;
    int wv = t >> 6, L = t & 63;
    int n = blockIdx.x * 8 + wv * 2 + (L >> 5);
    int g = (L >> 3) & 3, o = L & 7;
    AGG_LOOP()

    if (g == 0) {
        float inv = 1.f / (ssum + 1e-16f);
        float4 bv0 = b4[2 * o], bv1 = b4[2 * o + 1];
        float4 r0, r1;
        r0.x = acc[0] * inv + bv0.x; r0.y = acc[1] * inv + bv0.y;
        r0.z = acc[2] * inv + bv0.z; r0.w = acc[3] * inv + bv0.w;
        r1.x = acc[4] * inv + bv1.x; r1.y = acc[5] * inv + bv1.y;
        r1.z = acc[6] * inv + bv1.z; r1.w = acc[7] * inv + bv1.w;
        if (apply_elu) {
            r0.x = (r0.x > 0.f) ? r0.x : (__expf(r0.x) - 1.f);
            r0.y = (r0.y > 0.f) ? r0.y : (__expf(r0.y) - 1.f);
            r0.z = (r0.z > 0.f) ? r0.z : (__expf(r0.z) - 1.f);
            r0.w = (r0.w > 0.f) ? r0.w : (__expf(r0.w) - 1.f);
            r1.x = (r1.x > 0.f) ? r1.x : (__expf(r1.x) - 1.f);
            r1.y = (r1.y > 0.f) ? r1.y : (__expf(r1.y) - 1.f);
            r1.z = (r1.z > 0.f) ? r1.z : (__expf(r1.z) - 1.f);
            r1.w = (r1.w > 0.f) ? r1.w : (__expf(r1.w) - 1.f);
        }
        out4[n * 16 + 2 * o] = r0;
        out4[n * 16 + 2 * o + 1] = r1;
    }
}

// ----------------------------------------- aggregation + NEXT-LAYER GEMM fused
// Layers 0-2: agg output row (bias+ELU) is NODE-LOCAL input to the next
// layer's GEMM -> keep it in LDS, run the 64x64 GEMM as an epilogue in the
// same half-wave (lane = 2 features), write h/es/ed for the next layer.
// Deletes 3 gemm dispatches + act0/act1 global round-trips. W_next staged
// per block in pair-interleaved LDS layout wTp[li*132 + k*2 + c] =
// W[k][2*li+c] (stride 132 floats: 16B-aligned b128 rows, <=4-way banks).
__global__ __launch_bounds__(256) void aggemm_kernel(
    const uint4* __restrict__ h8, const float* __restrict__ es_in,
    const float* __restrict__ ed_in, const int* __restrict__ rowptr,
    const unsigned short* __restrict__ csr, const float4* __restrict__ b4,
    const float* __restrict__ Wn, const float* __restrict__ attn,
    _Float16* __restrict__ h_out, float* __restrict__ es_out,
    float* __restrict__ ed_out) {
    __shared__ alignas(16) float wTp[32 * 132];
    __shared__ alignas(16) float outs[8][64];
    int t = threadIdx.x;
    {   // stage W_next (16 KB) -> LDS; issues early, covered by agg latency
        const float4* W4 = (const float4*)Wn;
#pragma unroll
        for (int q = 0; q < 4; q++) {
            int idx4 = q * 256 + t;      // 1024 float4 = 4096 floats
            float4 wv4 = W4[idx4];
            int base = idx4 << 2;
            int k = base >> 6, fb = base & 63;   // fb multiple of 4
            float2* p0 = (float2*)&wTp[(fb >> 1) * 132 + k * 2];
            float2* p1 = (float2*)&wTp[((fb >> 1) + 1) * 132 + k * 2];
            p0->x = wv4.x; p0->y = wv4.y;
            p1->x = wv4.z; p1->y = wv4.w;
        }
    }
    int wv = t >> 6, L = t & 63;
    int slot = wv * 2 + (L >> 5);
    int n = blockIdx.x * 8 + slot;
    int g = (L >> 3) & 3, o = L & 7;
    AGG_LOOP()

    if (g == 0) {   // bias + ELU (always: intermediate layers), row -> LDS
        float inv = 1.f / (ssum + 1e-16f);
        float4 bv0 = b4[2 * o], bv1 = b4[2 * o + 1];
        float4 r0, r1;
        r0.x = acc[0] * inv + bv0.x; r0.y = acc[1] * inv + bv0.y;
        r0.z = acc[2] * inv + bv0.z; r0.w = acc[3] * inv + bv0.w;
        r1.x = acc[4] * inv + bv1.x; r1.y = acc[5] * inv + bv1.y;
        r1.z = acc[6] * inv + bv1.z; r1.w = acc[7] * inv + bv1.w;
        r0.x = (r0.x > 0.f) ? r0.x : (__expf(r0.x) - 1.f);
        r0.y = (r0.y > 0.f) ? r0.y : (__expf(r0.y) - 1.f);
        r0.z = (r0.z > 0.f) ? r0.z : (__expf(r0.z) - 1.f);
        r0.w = (r0.w > 0.f) ? r0.w : (__expf(r0.w) - 1.f);
        r1.x = (r1.x > 0.f) ? r1.x : (__expf(r1.x) - 1.f);
        r1.y = (r1.y > 0.f) ? r1.y : (__expf(r1.y) - 1.f);
        r1.z = (r1.z > 0.f) ? r1.z : (__expf(r1.z) - 1.f);
        r1.w = (r1.w > 0.f) ? r1.w : (__expf(r1.w) - 1.f);
        float4* os = (float4*)&outs[slot][0];
        os[2 * o] = r0;
        os[2 * o + 1] = r1;
    }
    __syncthreads();

    // epilogue GEMM: lane covers features f0, f0+1 of the next layer
    int li = L & 31;
    int f0 = li << 1;
    const float* wrow = &wTp[li * 132];
    float h0 = 0.f, h1 = 0.f;
#pragma unroll
    for (int k4 = 0; k4 < 64; k4 += 4) {
        float4 ov = *(const float4*)&outs[slot][k4];       // broadcast/half
        float4 wa = *(const float4*)&wrow[k4 * 2];         // k4,k4+1 pairs
        float4 wb = *(const float4*)&wrow[k4 * 2 + 4];     // k4+2,k4+3 pairs
        h0 += ov.x * wa.x + ov.y * wa.z + ov.z * wb.x + ov.w * wb.z;
        h1 += ov.x * wa.y + ov.y * wa.w + ov.z * wb.y + ov.w * wb.w;
    }
    // attention logits for next layer (4-lane tree per head)
    float sa = h0 * attn[f0] + h1 * attn[f0 + 1];
    float da = h0 * attn[64 + f0] + h1 * attn[64 + f0 + 1];
    sa += __shfl_xor(sa, 1); sa += __shfl_xor(sa, 2);
    da += __shfl_xor(da, 1); da += __shfl_xor(da, 2);
    if ((li & 3) == 0) {
        int hh = li >> 2;
        es_out[n * NH + hh] = sa;
        ed_out[n * NH + hh] = da;
    }
    union { _Float16 hf[2]; unsigned u; } cv;
    cv.hf[0] = (_Float16)h0;
    cv.hf[1] = (_Float16)h1;
    *(unsigned*)(h_out + (size_t)n * HD + f0) = cv.u;
}

// ---------------------------------------------------------------- launcher
extern "C" void kernel_launch(void* const* d_in, const int* in_sizes, int n_in,
                              void* d_out, int out_size, void* d_ws, size_t ws_size,
                              hipStream_t stream) {
    const float* x   = (const float*)d_in[0];
    const int*   ei  = (const int*)d_in[1];
    const int*   src = ei;
    const int*   dst = ei + N_EDGES;
    const float* W[4]   = {(const float*)d_in[2], (const float*)d_in[5],
                           (const float*)d_in[8], (const float*)d_in[11]};
    const float* att[4] = {(const float*)d_in[3], (const float*)d_in[6],
                           (const float*)d_in[9], (const float*)d_in[12]};
    const float* bb[4]  = {(const float*)d_in[4], (const float*)d_in[7],
                           (const float*)d_in[10], (const float*)d_in[13]};

    char* wsb = (char*)d_ws;
    size_t off = 0;
    auto alloc = [&](size_t bytes) -> void* {
        size_t a = (off + 255) & ~(size_t)255;
        off = a + bytes;
        return (void*)(wsb + a);
    };
    int*            offs   = (int*)alloc((size_t)SCAN_M * 4);
    int*            part2  = (int*)alloc((size_t)NB2 * 4);
    unsigned*       ebuf   = (unsigned*)alloc((size_t)N_EDGES * 4);
    int*            rowptr = (int*)alloc((size_t)(N_NODES + 1) * 4);
    unsigned short* csr    = (unsigned short*)alloc((size_t)N_EDGES * 2);
    _Float16*       h_a    = (_Float16*)alloc((size_t)N_NODES * HD * 2);
    float*          es_a   = (float*)alloc((size_t)N_NODES * NH * 4);
    float*          ed_a   = (float*)alloc((size_t)N_NODES * NH * 4);
    _Float16*       h_b    = (_Float16*)alloc((size_t)N_NODES * HD * 2);
    float*          es_b   = (float*)alloc((size_t)N_NODES * NH * 4);
    float*          ed_b   = (float*)alloc((size_t)N_NODES * NH * 4);

    const int GA = N_NODES / 8;  // 6250 blocks, 8 nodes per block
    const dim3 GF(GBN, 5);       // y<4: gemm layer0, y==4: histA

    // CSR build + layer-0 GEMM fused (independent work overlapped)
    histA_gemm_kernel<<<GF, 256, 0, stream>>>(dst, offs, x, W[0], att[0],
                                              h_a, es_a, ed_a);
    scanB1_kernel<<<NB2, 256, 0, stream>>>(offs, part2);
    scatC_kernel<<<GB1, 256, 0, stream>>>(src, dst, offs, part2, ebuf);
    csrD_kernel<<<NBKT, 512, 0, stream>>>(offs, part2, ebuf, rowptr, csr);

    // layers 0-2: agg + fused next-layer GEMM (double-buffered h/es/ed)
    aggemm_kernel<<<GA, 256, 0, stream>>>((const uint4*)h_a, es_a, ed_a,
                                          rowptr, csr, (const float4*)bb[0],
                                          W[1], att[1], h_b, es_b, ed_b);
    aggemm_kernel<<<GA, 256, 0, stream>>>((const uint4*)h_b, es_b, ed_b,
                                          rowptr, csr, (const float4*)bb[1],
                                          W[2], att[2], h_a, es_a, ed_a);
    aggemm_kernel<<<GA, 256, 0, stream>>>((const uint4*)h_a, es_a, ed_a,
                                          rowptr, csr, (const float4*)bb[2],
                                          W[3], att[3], h_b, es_b, ed_b);
    // final layer: plain agg -> d_out (no ELU)
    agg_kernel<<<GA, 256, 0, stream>>>((const uint4*)h_b, es_b, ed_b,
                                       rowptr, csr, (const float4*)bb[3],
                                       (float4*)d_out, 0);
}

// Round 9
// 293.795 us; speedup vs baseline: 1.2452x; 1.0353x over previous
//
#include <hip/hip_runtime.h>

#define N_NODES 50000
#define N_EDGES 1600000
#define HD 64    // H*D
#define NH 8     // heads
#define NBKT 196 // dst buckets (dst >> 8)
#define EPB 8192 // edges per block in binning passes
#define GB1 196  // ceil(N_EDGES / EPB)
#define SCAN_M (NBKT * GB1)   // 38416
#define NB2 151               // ceil(SCAN_M / 256)
#define DCAP 8960             // pass-D LDS edge capacity (mean 8192, +8.5 sigma)
#define SEGB 2048             // 256 dst-low bins x 8 src segments
#define GBN 196               // ceil(N_NODES / 256) node blocks for gemm

__device__ inline int wave_incl_scan(int v, int lane) {
#pragma unroll
    for (int o = 1; o < 64; o <<= 1) {
        int t = __shfl_up(v, o);
        if (lane >= o) v += t;
    }
    return v;
}

// ------------------------------------------------- GEMM + attention logits
// PROVEN config: thread = node, 16 output features (= 2 complete heads),
// 4 y-blocks. x re-reads are L3-absorbed; narrow tile keeps VGPR/SGPR
// pressure low -> deep load pipelining. 32/64-wide measured SLOWER.
// (Only used for layer 0 now; layers 1-3 GEMMs are fused into aggemm.)
template <int F>
__device__ __forceinline__ void gemm_body16(
    int bx, int by, int t,
    const float* __restrict__ x, const float* __restrict__ W,
    const float* __restrict__ att,
    _Float16* __restrict__ h, float* __restrict__ es, float* __restrict__ ed) {
    int n = bx * 256 + t;
    int f0 = by * 16;
    int nc = (n < N_NODES) ? n : (N_NODES - 1);
    const float4* xrow = (const float4*)x + (size_t)nc * (F / 4);
    float acc[16];
#pragma unroll
    for (int i = 0; i < 16; i++) acc[i] = 0.f;
#pragma unroll 4
    for (int kk = 0; kk < F / 4; kk++) {
        float4 xv = xrow[kk];
        const float* Wk = W + (kk * 4) * 64 + f0;  // wave-uniform base
#pragma unroll
        for (int i = 0; i < 16; i++)
            acc[i] += xv.x * Wk[i] + xv.y * Wk[64 + i] +
                      xv.z * Wk[128 + i] + xv.w * Wk[192 + i];
    }
    if (n >= N_NODES) return;

    float s0 = 0.f, s1 = 0.f, d0 = 0.f, d1 = 0.f;
#pragma unroll
    for (int i = 0; i < 8; i++) {
        s0 += acc[i] * att[f0 + i];
        d0 += acc[i] * att[64 + f0 + i];
    }
#pragma unroll
    for (int i = 8; i < 16; i++) {
        s1 += acc[i] * att[f0 + i];
        d1 += acc[i] * att[64 + f0 + i];
    }
    int hh = f0 >> 3;
    es[n * NH + hh] = s0; es[n * NH + hh + 1] = s1;
    ed[n * NH + hh] = d0; ed[n * NH + hh + 1] = d1;

    union { _Float16 hf[16]; uint4 u[2]; } cv;
#pragma unroll
    for (int i = 0; i < 16; i++) cv.hf[i] = (_Float16)acc[i];
    uint4* hp = (uint4*)(h + (size_t)n * HD + f0);
    hp[0] = cv.u[0];
    hp[1] = cv.u[1];
}

// ---------------------------------------------------- CSR build (no global atomics)
// Fused: grid (GBN, 5). y<4 -> gemm layer0 y-block (hides histA); y==4 ->
// dst histogram block (GB1 == GBN == 196).
__global__ __launch_bounds__(256) void histA_gemm_kernel(
    const int* __restrict__ dst, int* __restrict__ offs,
    const float* __restrict__ x, const float* __restrict__ W,
    const float* __restrict__ att,
    _Float16* __restrict__ h, float* __restrict__ es, float* __restrict__ ed) {
    if (blockIdx.y < 4) {
        gemm_body16<128>(blockIdx.x, blockIdx.y, threadIdx.x, x, W, att, h, es, ed);
        return;
    }
    int bb = blockIdx.x;
    __shared__ int hist[NBKT];
    int t = threadIdx.x;
    if (t < NBKT) hist[t] = 0;
    __syncthreads();
    int base = bb * EPB;
#pragma unroll
    for (int k = 0; k < EPB / 256; k++) {
        int e = base + k * 256 + t;
        if (e < N_EDGES) atomicAdd(&hist[dst[e] >> 8], 1);
    }
    __syncthreads();
    if (t < NBKT) offs[t * GB1 + bb] = hist[t];
}

__global__ __launch_bounds__(256) void scanB1_kernel(int* __restrict__ offs,
                                                     int* __restrict__ part2) {
    __shared__ int wsum[4];
    int t = threadIdx.x, lane = t & 63, wv = t >> 6;
    int i = blockIdx.x * 256 + t;
    int v = (i < SCAN_M) ? offs[i] : 0;
    int inc = wave_incl_scan(v, lane);
    if (lane == 63) wsum[wv] = inc;
    __syncthreads();
    if (t == 0) {
        int a = 0;
        for (int k = 0; k < 4; k++) { int x = wsum[k]; wsum[k] = a; a += x; }
    }
    __syncthreads();
    int excl = wsum[wv] + inc - v;
    if (i < SCAN_M) offs[i] = excl;
    if (t == 255) part2[blockIdx.x] = wsum[wv] + inc;
}

// scanB2 folded into consumers: each block exclusive-scans part2 (151 ints) in LDS.
__global__ __launch_bounds__(256) void scatC_kernel(const int* __restrict__ src,
                                                    const int* __restrict__ dst,
                                                    const int* __restrict__ offs,
                                                    const int* __restrict__ part2,
                                                    unsigned* __restrict__ ebuf) {
    __shared__ int cur[NBKT];
    __shared__ int base_s[NBKT];
    __shared__ int p2s[256];
    __shared__ int p2w[4];
    int t = threadIdx.x, lane = t & 63, wv = t >> 6;
    int v = (t < NB2) ? part2[t] : 0;
    int inc = wave_incl_scan(v, lane);
    if (lane == 63) p2w[wv] = inc;
    __syncthreads();
    if (t == 0) {
        int a = 0;
        for (int k = 0; k < 4; k++) { int x = p2w[k]; p2w[k] = a; a += x; }
    }
    __syncthreads();
    p2s[t] = p2w[wv] + inc - v;
    if (t < NBKT) cur[t] = 0;
    __syncthreads();
    if (t < NBKT) {
        int f = t * GB1 + blockIdx.x;
        base_s[t] = offs[f] + p2s[f >> 8];
    }
    __syncthreads();
    int base = blockIdx.x * EPB;
#pragma unroll
    for (int k = 0; k < EPB / 256; k++) {
        int e = base + k * 256 + t;
        if (e < N_EDGES) {
            int d = dst[e];
            int b = d >> 8;
            int r = atomicAdd(&cur[b], 1);
            ebuf[base_s[b] + r] = (unsigned)src[e] | ((unsigned)(d & 255) << 16);
        }
    }
}

__global__ __launch_bounds__(512) void csrD_kernel(const int* __restrict__ offs,
                                                   const int* __restrict__ part2,
                                                   const unsigned* __restrict__ ebuf,
                                                   int* __restrict__ rowptr,
                                                   unsigned short* __restrict__ csr) {
    __shared__ unsigned eb[DCAP];
    __shared__ int hist[SEGB];
    __shared__ int wsum[8];
    __shared__ int p2s[512];
    int b = blockIdx.x, t = threadIdx.x;
    int lane = t & 63, wv = t >> 6;
    {   // in-block exclusive scan of part2 (replaces scanB2 dispatch)
        int v = (t < NB2) ? part2[t] : 0;
        int inc = wave_incl_scan(v, lane);
        if (lane == 63) wsum[wv] = inc;
        __syncthreads();
        if (t == 0) {
            int a = 0;
            for (int k = 0; k < 8; k++) { int x = wsum[k]; wsum[k] = a; a += x; }
        }
        __syncthreads();
        p2s[t] = wsum[wv] + inc - v;
        __syncthreads();
    }
    int f0 = b * GB1;
    int base = offs[f0] + p2s[f0 >> 8];
    int nxt;
    if (b == NBKT - 1) nxt = N_EDGES;
    else { int f1 = (b + 1) * GB1; nxt = offs[f1] + p2s[f1 >> 8]; }
    int nb = nxt - base;
    if (nb > DCAP) nb = DCAP;  // statistically impossible; guards LDS OOB
    for (int i = t; i < SEGB; i += 512) hist[i] = 0;
    __syncthreads();
    for (int i = t; i < nb; i += 512) {
        unsigned v = ebuf[base + i];
        eb[i] = v;
        int bin = (int)((v >> 16) << 3) | (int)((v & 0xFFFFu) >> 13);
        atomicAdd(&hist[bin], 1);
    }
    __syncthreads();
    int b0 = t << 2;
    int loc0 = hist[b0], loc1 = hist[b0 + 1], loc2 = hist[b0 + 2], loc3 = hist[b0 + 3];
    int s = loc0 + loc1 + loc2 + loc3;
    int inc = wave_incl_scan(s, lane);
    if (lane == 63) wsum[wv] = inc;
    __syncthreads();
    if (t == 0) {
        int a = 0;
        for (int k = 0; k < 8; k++) { int x = wsum[k]; wsum[k] = a; a += x; }
    }
    __syncthreads();
    int run = wsum[wv] + inc - s;
    hist[b0] = run; run += loc0;
    hist[b0 + 1] = run; run += loc1;
    hist[b0 + 2] = run; run += loc2;
    hist[b0 + 3] = run;
    __syncthreads();
    if (t < 256) {
        int node = b * 256 + t;
        if (node < N_NODES) rowptr[node] = base + hist[t << 3];
    }
    if (b == 0 && t == 0) rowptr[N_NODES] = N_EDGES;
    __syncthreads();
    for (int i = t; i < nb; i += 512) {
        unsigned v = eb[i];
        int bin = (int)((v >> 16) << 3) | (int)((v & 0xFFFFu) >> 13);
        int r = atomicAdd(&hist[bin], 1);
        csr[base + r] = (unsigned short)(v & 0xFFFFu);
    }
}

// ---------------------------------------------- fused f16*f32+f32 accumulate
// v_fma_mix_f32: D.f32 = f16(half of S0) * S1.f32 + S2.f32 -- replaces the
// cvt_f32_f16 + fma pair (bitwise-identical arithmetic, half the VALU ops).
// NOTE (r7/r8 compile fails): asm operands must be plain scalar locals, and
// macro parameter must NOT be named `w` (token-substitutes into `.w`!).
__device__ __forceinline__ void fmamix2(float& alo, float& ahi, unsigned dw,
                                        float wgt) {
    asm("v_fma_mix_f32 %0, %2, %3, %0 op_sel_hi:[1,0,0]"
        : "=v"(alo) : "0"(alo), "v"(dw), "v"(wgt));
    asm("v_fma_mix_f32 %0, %2, %3, %0 op_sel:[1,0,0] op_sel_hi:[1,0,0]"
        : "=v"(ahi) : "0"(ahi), "v"(dw), "v"(wgt));
}

#define EDGE_ACC(hv, wgt) do {                                               \
    unsigned _d0 = (hv).x, _d1 = (hv).y, _d2 = (hv).z, _d3 = (hv).w;         \
    float _w = (wgt);                                                        \
    fmamix2(acc[0], acc[1], _d0, _w);                                        \
    fmamix2(acc[2], acc[3], _d1, _w);                                        \
    fmamix2(acc[4], acc[5], _d2, _w);                                        \
    fmamix2(acc[6], acc[7], _d3, _w);                                        \
} while (0)

// ---------------------------------------------- agg loop (shared by both kernels)
// SPLIT-WAVE: each HALF-WAVE (32 lanes = 4 edge slots x 8 heads) owns one
// node with its OWN exact trip count. Proven round-5 structure; inner
// accumulate now via v_fma_mix (64 -> 32 VALU ops per 16-edge batch).
#define AGG_LOOP()                                                          \
    int beg = rowptr[n], end = rowptr[n + 1];                               \
    float edn = ed_in[n * NH + o];                                          \
    int last = (end > beg) ? (end - 1) : 0;                                 \
    float acc[8] = {0.f, 0.f, 0.f, 0.f, 0.f, 0.f, 0.f, 0.f};                \
    float ssum = 0.f;                                                       \
    int j = beg;                                                            \
    for (; j + 16 <= end; j += 16) {                                        \
        int s0 = csr[j + g];                                                \
        int s1 = csr[j + 4 + g];                                            \
        int s2 = csr[j + 8 + g];                                            \
        int s3 = csr[j + 12 + g];                                           \
        uint4 hv0 = h8[s0 * 8 + o];                                         \
        uint4 hv1 = h8[s1 * 8 + o];                                         \
        uint4 hv2 = h8[s2 * 8 + o];                                         \
        uint4 hv3 = h8[s3 * 8 + o];                                         \
        float ev0 = es_in[s0 * NH + o];                                     \
        float ev1 = es_in[s1 * NH + o];                                     \
        float ev2 = es_in[s2 * NH + o];                                     \
        float ev3 = es_in[s3 * NH + o];                                     \
        float e0 = ev0 + edn; e0 = (e0 > 0.f) ? e0 : 0.2f * e0;             \
        float e1 = ev1 + edn; e1 = (e1 > 0.f) ? e1 : 0.2f * e1;             \
        float e2 = ev2 + edn; e2 = (e2 > 0.f) ? e2 : 0.2f * e2;             \
        float e3 = ev3 + edn; e3 = (e3 > 0.f) ? e3 : 0.2f * e3;             \
        float w0 = __expf(e0), w1 = __expf(e1);                             \
        float w2 = __expf(e2), w3 = __expf(e3);                             \
        EDGE_ACC(hv0, w0);                                                  \
        EDGE_ACC(hv1, w1);                                                  \
        EDGE_ACC(hv2, w2);                                                  \
        EDGE_ACC(hv3, w3);                                                  \
        ssum += w0 + w1;                                                    \
        ssum += w2 + w3;                                                    \
    }                                                                       \
    if (j < end) {                                                          \
        int i0 = j + g, i1 = j + 4 + g, i2 = j + 8 + g, i3 = j + 12 + g;    \
        int s0 = csr[(i0 < end) ? i0 : last];                               \
        int s1 = csr[(i1 < end) ? i1 : last];                               \
        int s2 = csr[(i2 < end) ? i2 : last];                               \
        int s3 = csr[(i3 < end) ? i3 : last];                               \
        uint4 hv0 = h8[s0 * 8 + o];                                         \
        uint4 hv1 = h8[s1 * 8 + o];                                         \
        uint4 hv2 = h8[s2 * 8 + o];                                         \
        uint4 hv3 = h8[s3 * 8 + o];                                         \
        float ev0 = es_in[s0 * NH + o];                                     \
        float ev1 = es_in[s1 * NH + o];                                     \
        float ev2 = es_in[s2 * NH + o];                                     \
        float ev3 = es_in[s3 * NH + o];                                     \
        float e0 = ev0 + edn; e0 = (e0 > 0.f) ? e0 : 0.2f * e0;             \
        float e1 = ev1 + edn; e1 = (e1 > 0.f) ? e1 : 0.2f * e1;             \
        float e2 = ev2 + edn; e2 = (e2 > 0.f) ? e2 : 0.2f * e2;             \
        float e3 = ev3 + edn; e3 = (e3 > 0.f) ? e3 : 0.2f * e3;             \
        float w0 = (i0 < end) ? __expf(e0) : 0.f;                           \
        float w1 = (i1 < end) ? __expf(e1) : 0.f;                           \
        float w2 = (i2 < end) ? __expf(e2) : 0.f;                           \
        float w3 = (i3 < end) ? __expf(e3) : 0.f;                           \
        EDGE_ACC(hv0, w0);                                                  \
        EDGE_ACC(hv1, w1);                                                  \
        EDGE_ACC(hv2, w2);                                                  \
        EDGE_ACC(hv3, w3);                                                  \
        ssum += w0 + w1;                                                    \
        ssum += w2 + w3;                                                    \
    }                                                                       \
    _Pragma("unroll")                                                       \
    for (int i = 0; i < 8; i++) {                                           \
        acc[i] += __shfl_xor(acc[i], 8);                                    \
        acc[i] += __shfl_xor(acc[i], 16);                                   \
    }                                                                       \
    ssum += __shfl_xor(ssum, 8);                                            \
    ssum += __shfl_xor(ssum, 16);

// ------------------------------------------------------------- aggregation
// Final layer: plain agg -> d_out, no ELU.
__global__ __launch_bounds__(256) void agg_kernel(
    const uint4* __restrict__ h8, const float* __restrict__ es_in,
    const float* __restrict__ ed_in, const int* __restrict__ rowptr,
    const unsigned short* __restrict__ csr, const float4* __restrict__ b4,
    float4* __restrict__ out4, int apply_elu) {
    int t = threadIdx.x;
    int wv = t >> 6, L = t & 63;
    int n = blockIdx.x * 8 + wv * 2 + (L >> 5);
    int g = (L >> 3) & 3, o = L & 7;
    AGG_LOOP()

    if (g == 0) {
        float inv = 1.f / (ssum + 1e-16f);
        float4 bv0 = b4[2 * o], bv1 = b4[2 * o + 1];
        float4 r0, r1;
        r0.x = acc[0] * inv + bv0.x; r0.y = acc[1] * inv + bv0.y;
        r0.z = acc[2] * inv + bv0.z; r0.w = acc[3] * inv + bv0.w;
        r1.x = acc[4] * inv + bv1.x; r1.y = acc[5] * inv + bv1.y;
        r1.z = acc[6] * inv + bv1.z; r1.w = acc[7] * inv + bv1.w;
        if (apply_elu) {
            r0.x = (r0.x > 0.f) ? r0.x : (__expf(r0.x) - 1.f);
            r0.y = (r0.y > 0.f) ? r0.y : (__expf(r0.y) - 1.f);
            r0.z = (r0.z > 0.f) ? r0.z : (__expf(r0.z) - 1.f);
            r0.w = (r0.w > 0.f) ? r0.w : (__expf(r0.w) - 1.f);
            r1.x = (r1.x > 0.f) ? r1.x : (__expf(r1.x) - 1.f);
            r1.y = (r1.y > 0.f) ? r1.y : (__expf(r1.y) - 1.f);
            r1.z = (r1.z > 0.f) ? r1.z : (__expf(r1.z) - 1.f);
            r1.w = (r1.w > 0.f) ? r1.w : (__expf(r1.w) - 1.f);
        }
        out4[n * 16 + 2 * o] = r0;
        out4[n * 16 + 2 * o + 1] = r1;
    }
}

// ----------------------------------------- aggregation + NEXT-LAYER GEMM fused
// Layers 0-2: agg output row (bias+ELU) is NODE-LOCAL input to the next
// layer's GEMM -> keep it in LDS, run the 64x64 GEMM as an epilogue in the
// same half-wave (lane = 2 features), write h/es/ed for the next layer.
// W_next staged per block in pair-interleaved LDS layout wTp[li*132+k*2+c]
// = W[k][2*li+c] (stride 132 floats: 16B-aligned b128 rows, <=4-way banks).
__global__ __launch_bounds__(256) void aggemm_kernel(
    const uint4* __restrict__ h8, const float* __restrict__ es_in,
    const float* __restrict__ ed_in, const int* __restrict__ rowptr,
    const unsigned short* __restrict__ csr, const float4* __restrict__ b4,
    const float* __restrict__ Wn, const float* __restrict__ attn,
    _Float16* __restrict__ h_out, float* __restrict__ es_out,
    float* __restrict__ ed_out) {
    __shared__ alignas(16) float wTp[32 * 132];
    __shared__ alignas(16) float outs[8][64];
    int t = threadIdx.x;
    {   // stage W_next (16 KB) -> LDS; issues early, covered by agg latency
        const float4* W4 = (const float4*)Wn;
#pragma unroll
        for (int q = 0; q < 4; q++) {
            int idx4 = q * 256 + t;      // 1024 float4 = 4096 floats
            float4 wv4 = W4[idx4];
            int base = idx4 << 2;
            int k = base >> 6, fb = base & 63;   // fb multiple of 4
            float2* p0 = (float2*)&wTp[(fb >> 1) * 132 + k * 2];
            float2* p1 = (float2*)&wTp[((fb >> 1) + 1) * 132 + k * 2];
            p0->x = wv4.x; p0->y = wv4.y;
            p1->x = wv4.z; p1->y = wv4.w;
        }
    }
    int wv = t >> 6, L = t & 63;
    int slot = wv * 2 + (L >> 5);
    int n = blockIdx.x * 8 + slot;
    int g = (L >> 3) & 3, o = L & 7;
    AGG_LOOP()

    if (g == 0) {   // bias + ELU (always: intermediate layers), row -> LDS
        float inv = 1.f / (ssum + 1e-16f);
        float4 bv0 = b4[2 * o], bv1 = b4[2 * o + 1];
        float4 r0, r1;
        r0.x = acc[0] * inv + bv0.x; r0.y = acc[1] * inv + bv0.y;
        r0.z = acc[2] * inv + bv0.z; r0.w = acc[3] * inv + bv0.w;
        r1.x = acc[4] * inv + bv1.x; r1.y = acc[5] * inv + bv1.y;
        r1.z = acc[6] * inv + bv1.z; r1.w = acc[7] * inv + bv1.w;
        r0.x = (r0.x > 0.f) ? r0.x : (__expf(r0.x) - 1.f);
        r0.y = (r0.y > 0.f) ? r0.y : (__expf(r0.y) - 1.f);
        r0.z = (r0.z > 0.f) ? r0.z : (__expf(r0.z) - 1.f);
        r0.w = (r0.w > 0.f) ? r0.w : (__expf(r0.w) - 1.f);
        r1.x = (r1.x > 0.f) ? r1.x : (__expf(r1.x) - 1.f);
        r1.y = (r1.y > 0.f) ? r1.y : (__expf(r1.y) - 1.f);
        r1.z = (r1.z > 0.f) ? r1.z : (__expf(r1.z) - 1.f);
        r1.w = (r1.w > 0.f) ? r1.w : (__expf(r1.w) - 1.f);
        float4* os = (float4*)&outs[slot][0];
        os[2 * o] = r0;
        os[2 * o + 1] = r1;
    }
    __syncthreads();

    // epilogue GEMM: lane covers features f0, f0+1 of the next layer
    int li = L & 31;
    int f0 = li << 1;
    const float* wrow = &wTp[li * 132];
    float h0 = 0.f, h1 = 0.f;
#pragma unroll
    for (int k4 = 0; k4 < 64; k4 += 4) {
        float4 ov = *(const float4*)&outs[slot][k4];       // broadcast/half
        float4 wa = *(const float4*)&wrow[k4 * 2];         // k4,k4+1 pairs
        float4 wb = *(const float4*)&wrow[k4 * 2 + 4];     // k4+2,k4+3 pairs
        h0 += ov.x * wa.x + ov.y * wa.z + ov.z * wb.x + ov.w * wb.z;
        h1 += ov.x * wa.y + ov.y * wa.w + ov.z * wb.y + ov.w * wb.w;
    }
    // attention logits for next layer (4-lane tree per head)
    float sa = h0 * attn[f0] + h1 * attn[f0 + 1];
    float da = h0 * attn[64 + f0] + h1 * attn[64 + f0 + 1];
    sa += __shfl_xor(sa, 1); sa += __shfl_xor(sa, 2);
    da += __shfl_xor(da, 1); da += __shfl_xor(da, 2);
    if ((li & 3) == 0) {
        int hh = li >> 2;
        es_out[n * NH + hh] = sa;
        ed_out[n * NH + hh] = da;
    }
    union { _Float16 hf[2]; unsigned u; } cv;
    cv.hf[0] = (_Float16)h0;
    cv.hf[1] = (_Float16)h1;
    *(unsigned*)(h_out + (size_t)n * HD + f0) = cv.u;
}

// ---------------------------------------------------------------- launcher
extern "C" void kernel_launch(void* const* d_in, const int* in_sizes, int n_in,
                              void* d_out, int out_size, void* d_ws, size_t ws_size,
                              hipStream_t stream) {
    const float* x   = (const float*)d_in[0];
    const int*   ei  = (const int*)d_in[1];
    const int*   src = ei;
    const int*   dst = ei + N_EDGES;
    const float* W[4]   = {(const float*)d_in[2], (const float*)d_in[5],
                           (const float*)d_in[8], (const float*)d_in[11]};
    const float* att[4] = {(const float*)d_in[3], (const float*)d_in[6],
                           (const float*)d_in[9], (const float*)d_in[12]};
    const float* bb[4]  = {(const float*)d_in[4], (const float*)d_in[7],
                           (const float*)d_in[10], (const float*)d_in[13]};

    char* wsb = (char*)d_ws;
    size_t off = 0;
    auto alloc = [&](size_t bytes) -> void* {
        size_t a = (off + 255) & ~(size_t)255;
        off = a + bytes;
        return (void*)(wsb + a);
    };
    int*            offs   = (int*)alloc((size_t)SCAN_M * 4);
    int*            part2  = (int*)alloc((size_t)NB2 * 4);
    unsigned*       ebuf   = (unsigned*)alloc((size_t)N_EDGES * 4);
    int*            rowptr = (int*)alloc((size_t)(N_NODES + 1) * 4);
    unsigned short* csr    = (unsigned short*)alloc((size_t)N_EDGES * 2);
    _Float16*       h_a    = (_Float16*)alloc((size_t)N_NODES * HD * 2);
    float*          es_a   = (float*)alloc((size_t)N_NODES * NH * 4);
    float*          ed_a   = (float*)alloc((size_t)N_NODES * NH * 4);
    _Float16*       h_b    = (_Float16*)alloc((size_t)N_NODES * HD * 2);
    float*          es_b   = (float*)alloc((size_t)N_NODES * NH * 4);
    float*          ed_b   = (float*)alloc((size_t)N_NODES * NH * 4);

    const int GA = N_NODES / 8;  // 6250 blocks, 8 nodes per block
    const dim3 GF(GBN, 5);       // y<4: gemm layer0, y==4: histA

    // CSR build + layer-0 GEMM fused (independent work overlapped)
    histA_gemm_kernel<<<GF, 256, 0, stream>>>(dst, offs, x, W[0], att[0],
                                              h_a, es_a, ed_a);
    scanB1_kernel<<<NB2, 256, 0, stream>>>(offs, part2);
    scatC_kernel<<<GB1, 256, 0, stream>>>(src, dst, offs, part2, ebuf);
    csrD_kernel<<<NBKT, 512, 0, stream>>>(offs, part2, ebuf, rowptr, csr);

    // layers 0-2: agg + fused next-layer GEMM (double-buffered h/es/ed)
    aggemm_kernel<<<GA, 256, 0, stream>>>((const uint4*)h_a, es_a, ed_a,
                                          rowptr, csr, (const float4*)bb[0],
                                          W[1], att[1], h_b, es_b, ed_b);
    aggemm_kernel<<<GA, 256, 0, stream>>>((const uint4*)h_b, es_b, ed_b,
                                          rowptr, csr, (const float4*)bb[1],
                                          W[2], att[2], h_a, es_a, ed_a);
    aggemm_kernel<<<GA, 256, 0, stream>>>((const uint4*)h_a, es_a, ed_a,
                                          rowptr, csr, (const float4*)bb[2],
                                          W[3], att[3], h_b, es_b, ed_b);
    // final layer: plain agg -> d_out (no ELU)
    agg_kernel<<<GA, 256, 0, stream>>>((const uint4*)h_b, es_b, ed_b,
                                       rowptr, csr, (const float4*)bb[3],
                                       (float4*)d_out, 0);
}